// Round 10
// baseline (213.503 us; speedup 1.0000x reference)
//
#include <hip/hip_runtime.h>

#define EPSF 1e-12f
#define GN 32
#define NPTS (GN * GN * GN)
#define NCOL (GN * GN)
#define FSPLIT 16   // face-splits
#define NCG 16      // column-groups of 64 columns
#define NBLK (NCG * FSPLIT)
#define NTHR 1024
#define FS 20       // floats per face record

__device__ __forceinline__ float dot_rn(const float* x, const float* y) {
    return __fadd_rn(__fadd_rn(__fmul_rn(x[0], y[0]), __fmul_rn(x[1], y[1])),
                     __fmul_rn(x[2], y[2]));
}
__device__ __forceinline__ float wmin64(float v) {
    for (int o = 32; o > 0; o >>= 1) v = fminf(v, __shfl_xor(v, o));
    return v;
}
__device__ __forceinline__ float wmax64(float v) {
    for (int o = 32; o > 0; o >>= 1) v = fmaxf(v, __shfl_xor(v, o));
    return v;
}
__device__ __forceinline__ float wsum64(float v) {
    for (int o = 32; o > 0; o >>= 1) v += __shfl_xor(v, o);
    return v;
}

// ---------------- node 1: prep kernel ----------------
// Inits combine buffers, computes bboxes -> hdr[5], writes face records.
// fd is written in a SEPARATE dispatch so k_main reads it via the scalar path.
__global__ void __launch_bounds__(NTHR) k_prep(
    const float* __restrict__ hv, int nh,
    const float* __restrict__ ov, int no,
    const int* __restrict__ faces, int nf,
    float* __restrict__ hdr, float* __restrict__ fd,
    unsigned* __restrict__ d2u, unsigned* __restrict__ parm,
    unsigned* __restrict__ counter)
{
    __shared__ float s_w[16][12];
    __shared__ float s_hdr[4];
    int t = threadIdx.x, lane = t & 63, wvid = t >> 6;

    for (int i = t; i < NPTS; i += NTHR) d2u[i] = 0x7f800000u;  // +inf bits
    if (t < NCOL) parm[t] = 0u;
    if (t == 0) *counter = 0u;

    // ---- both bboxes in one pass ----
    float hmn[3] = { INFINITY, INFINITY, INFINITY };
    float hmx[3] = { -INFINITY, -INFINITY, -INFINITY };
    float omn[3] = { INFINITY, INFINITY, INFINITY };
    float omx[3] = { -INFINITY, -INFINITY, -INFINITY };
    for (int i = t; i < nh; i += NTHR)
        for (int k = 0; k < 3; ++k) {
            float v = hv[3 * i + k];
            hmn[k] = fminf(hmn[k], v); hmx[k] = fmaxf(hmx[k], v);
        }
    for (int i = t; i < no; i += NTHR)
        for (int k = 0; k < 3; ++k) {
            float v = ov[3 * i + k];
            omn[k] = fminf(omn[k], v); omx[k] = fmaxf(omx[k], v);
        }
    for (int k = 0; k < 3; ++k) {
        hmn[k] = wmin64(hmn[k]); hmx[k] = wmax64(hmx[k]);
        omn[k] = wmin64(omn[k]); omx[k] = wmax64(omx[k]);
    }
    if (lane == 0)
        for (int k = 0; k < 3; ++k) {
            s_w[wvid][k] = hmn[k]; s_w[wvid][3 + k] = hmx[k];
            s_w[wvid][6 + k] = omn[k]; s_w[wvid][9 + k] = omx[k];
        }
    __syncthreads();
    if (wvid == 0) {
        float r[12];
        for (int c = 0; c < 12; ++c) {
            bool ismin = (c < 3) || (c >= 6 && c < 9);
            float v = (lane < 16) ? s_w[lane][c] : (ismin ? INFINITY : -INFINITY);
            r[c] = ismin ? wmin64(v) : wmax64(v);
        }
        if (lane == 0) {
            bool ovl = true;
            for (int k = 0; k < 3; ++k)
                ovl = ovl && (r[k] <= r[9 + k]) && (r[6 + k] <= r[3 + k]);
            float e0 = __fsub_rn(r[3], r[0]);
            float e1 = __fsub_rn(r[4], r[1]);
            float e2 = __fsub_rn(r[5], r[2]);
            float m = fmaxf(e0, fmaxf(e1, e2));
            s_hdr[0] = __fmul_rn(0.5f, __fadd_rn(r[0], r[3]));
            s_hdr[1] = __fmul_rn(0.5f, __fadd_rn(r[1], r[4]));
            s_hdr[2] = __fmul_rn(0.5f, __fadd_rn(r[2], r[5]));
            s_hdr[3] = __fmul_rn(0.6f, m);
            hdr[0] = s_hdr[0]; hdr[1] = s_hdr[1]; hdr[2] = s_hdr[2];
            hdr[3] = s_hdr[3]; hdr[4] = ovl ? 1.0f : 0.0f;
        }
    }
    __syncthreads();
    float cx = s_hdr[0], cy = s_hdr[1], cz = s_hdr[2], sc = s_hdr[3];

    // ---- face records ----
    const float qnan = __int_as_float(0x7FC00000);
    for (int f = t; f < nf; f += NTHR) {
        int ia = faces[3 * f + 0], ib = faces[3 * f + 1], ic = faces[3 * f + 2];
        float v0[3], v1[3], v2[3];
        for (int k = 0; k < 3; ++k) {
            float cen = (k == 0) ? cx : ((k == 1) ? cy : cz);
            v0[k] = __fdiv_rn(__fsub_rn(hv[3 * ia + k], cen), sc);
            v1[k] = __fdiv_rn(__fsub_rn(hv[3 * ib + k], cen), sc);
            v2[k] = __fdiv_rn(__fsub_rn(hv[3 * ic + k], cen), sc);
        }
        float e0[3], e1[3];
        for (int k = 0; k < 3; ++k) {
            e0[k] = __fsub_rn(v1[k], v0[k]);
            e1[k] = __fsub_rn(v2[k], v0[k]);
        }
        float a = dot_rn(e0, e0);
        float b = dot_rn(e0, e1);
        float cc = dot_rn(e1, e1);
        float det = __fsub_rn(__fmul_rn(a, cc), __fmul_rn(b, b));
        // NaN-poisoned reciprocals: NaN comparisons false -> ref's forced-false
        float inv_det = (det > EPSF) ? (1.0f / det) : qnan;
        float inv_a = 1.0f / ((a > EPSF) ? a : 1.0f);
        float inv_c = 1.0f / ((cc > EPSF) ? cc : 1.0f);
        float ee2 = __fsub_rn(__fadd_rn(a, cc), __fmul_rn(2.0f, b));
        float inv_ee2 = 1.0f / ((ee2 > EPSF) ? ee2 : 1.0f);
        float det2 = __fsub_rn(__fmul_rn(e0[0], e1[1]), __fmul_rn(e1[0], e0[1]));
        float inv_det2s = (fabsf(det2) > EPSF) ? (1.0f / det2) : qnan;
        float* o = fd + (size_t)f * FS;
        o[0] = v0[0]; o[1] = v0[1]; o[2] = v0[2];
        o[3] = e0[0]; o[4] = e0[1]; o[5] = e0[2];
        o[6] = e1[0]; o[7] = e1[1]; o[8] = e1[2];
        o[9] = a; o[10] = b; o[11] = cc;
        o[12] = inv_det; o[13] = inv_a; o[14] = inv_c;
        o[15] = ee2; o[16] = inv_ee2; o[17] = inv_det2s;
        o[18] = __fsub_rn(b, a); o[19] = 0.f;
    }
}

// ---------------- node 2: main kernel ----------------
// waves_per_eu(4,4): pins 4 waves/EU (our real occupancy: one 16-wave block
// per CU) -> 128-VGPR budget. R9 evidence: at 64 VGPRs the allocator spills
// dmin[32] to scratch (WRITE_SIZE 29MB = 256k threads x 128B) and the z-loop
// stalls on scratch reloads (VALU 33% vs R4's 67% at identical VALU-work).
__global__ void __attribute__((amdgpu_flat_work_group_size(NTHR, NTHR),
                               amdgpu_waves_per_eu(4, 4))) k_main(
    const float* __restrict__ fd, int nf,
    unsigned* __restrict__ d2u, unsigned* __restrict__ parm,
    unsigned* __restrict__ counter,
    const float* __restrict__ hdr,
    const float* __restrict__ ov, int no,
    float* __restrict__ out)
{
    __shared__ unsigned s_d2[2048];
    __shared__ unsigned s_pm[64];
    __shared__ float s_w[16][8];
    __shared__ unsigned s_last;

    int t = threadIdx.x, lane = t & 63, wvid = t >> 6;
    int fs = blockIdx.x >> 4;   // face-split id
    int cg = blockIdx.x & 15;   // column-group id
    const float step = 2.0f / 31.0f;

    for (int i = t; i < 2048; i += NTHR) s_d2[i] = 0x7f800000u;
    if (t < 64) s_pm[t] = 0u;
    __syncthreads();

    // ---------- phase C: z-folded hot loop, face fields via s_load ----------
    {
        int col = cg * 64 + lane;           // gy*32+gx
        int gx = col & 31, gy = col >> 5;
        float px = __fadd_rn(-1.0f, __fmul_rn((float)gx, step));
        float py = __fadd_rn(-1.0f, __fmul_rn((float)gy, step));

        int chunkB = (nf + FSPLIT - 1) / FSPLIT;
        int f0B = fs * chunkB;
        int f1B = min(nf, f0B + chunkB);
        int nloc = f1B - f0B;
        // contiguous balanced per-wave split (R4 form + R6 balance); bounds
        // readfirstlane'd -> scalar induction -> s_load face fields.
        int f0 = __builtin_amdgcn_readfirstlane(f0B + (wvid * nloc) / 16);
        int f1 = __builtin_amdgcn_readfirstlane(f0B + ((wvid + 1) * nloc) / 16);

        float dmin[32];
#pragma unroll
        for (int k = 0; k < 32; ++k) dmin[k] = 3.402823466e38f;
        unsigned cmask = 0u;

        for (int f = f0; f < f1; ++f) {
            const float* q = fd + (size_t)f * FS;   // wave-uniform -> s_load
            float v0x = q[0], v0y = q[1], v0z = q[2];
            float e0x = q[3], e0y = q[4], e0z = q[5];
            float e1x = q[6], e1y = q[7], e1z = q[8];
            float a = q[9], b = q[10], cc = q[11];
            float inv_det = q[12], inv_a = q[13], inv_c = q[14];
            float ee2 = q[15], inv_ee2 = q[16], inv_det2s = q[17];
            float bma = q[18];

            float wx = __fsub_rn(px, v0x), wy = __fsub_rn(py, v0y);
            float ffxy = wx * wx + wy * wy;
            float de0xy = wx * e0x + wy * e0y;
            float de1xy = wx * e1x + wy * e1y;

            float u2n = __fsub_rn(__fmul_rn(wx, e1y), __fmul_rn(wy, e1x));
            float v2n = __fsub_rn(__fmul_rn(e0x, wy), __fmul_rn(e0y, wx));
            float u2 = __fmul_rn(u2n, inv_det2s);
            float v2 = __fmul_rn(v2n, inv_det2s);
            bool in2d = (u2 >= 0.0f) & (v2 >= 0.0f) & (__fadd_rn(u2, v2) <= 1.0f);
            float zint = __fadd_rn(__fadd_rn(v0z, __fmul_rn(u2, e0z)), __fmul_rn(v2, e1z));
            int c = 0;
            {
                float p;
                p = __fadd_rn(-1.0f, __fmul_rn((float)(15), step));      if (zint > p) c = 16;
                p = __fadd_rn(-1.0f, __fmul_rn((float)(c + 7), step));   if (zint > p) c += 8;
                p = __fadd_rn(-1.0f, __fmul_rn((float)(c + 3), step));   if (zint > p) c += 4;
                p = __fadd_rn(-1.0f, __fmul_rn((float)(c + 1), step));   if (zint > p) c += 2;
                p = __fadd_rn(-1.0f, __fmul_rn((float)(c), step));       if (zint > p) c += 1;
                p = __fadd_rn(-1.0f, __fmul_rn((float)(c), step));       if (zint > p) c += 1;
            }
            unsigned mask = (c == 0) ? 0u : (0xffffffffu >> (32 - c));
            cmask ^= in2d ? mask : 0u;

#pragma unroll
            for (int k = 0; k < 32; ++k) {
                const float pzk = -1.0f + (float)k * (2.0f / 31.0f);
                float wz = __fsub_rn(pzk, v0z);
                float ff = fmaf(wz, wz, ffxy);
                float de0 = fmaf(wz, e0z, de0xy);
                float de1 = fmaf(wz, e1z, de1xy);
                float u = (cc * de0 - b * de1) * inv_det;
                float v = (a * de1 - b * de0) * inv_det;
                bool inside = (u >= 0.0f) & (v >= 0.0f) & (u + v <= 1.0f);
                float plane_d2 = ff - (u * de0 + v * de1);
                float t0 = fminf(fmaxf(de0 * inv_a, 0.0f), 1.0f);
                float d2_0 = ff + t0 * (t0 * a - 2.0f * de0);
                float t1 = fminf(fmaxf(de1 * inv_c, 0.0f), 1.0f);
                float d2_1 = ff + t1 * (t1 * cc - 2.0f * de1);
                float dot2 = (de1 - de0) - bma;
                float w1sq = ff - 2.0f * de0 + a;
                float t2 = fminf(fmaxf(dot2 * inv_ee2, 0.0f), 1.0f);
                float d2_2 = w1sq + t2 * (t2 * ee2 - 2.0f * dot2);
                float ed2 = fminf(fminf(d2_0, d2_1), d2_2);
                float d2 = inside ? plane_d2 : ed2;
                dmin[k] = fminf(dmin[k], fmaxf(d2, 0.0f));
            }
        }

        // block combine (LDS), then device-scope atomics into ws buffers
#pragma unroll
        for (int k = 0; k < 32; ++k)
            atomicMin(&s_d2[k * 64 + lane], __float_as_uint(dmin[k]));
        atomicXor(&s_pm[lane], cmask);
        __syncthreads();
        for (int i = t; i < 2048; i += NTHR) {
            int k = i >> 6, ln = i & 63;
            atomicMin(&d2u[k * NCOL + cg * 64 + ln], s_d2[i]);
        }
        if (t < 64) atomicXor(&parm[cg * 64 + t], s_pm[t]);
    }

    // ---------- completion counter: last block finishes ----------
    __threadfence();
    __syncthreads();
    if (t == 0) {
        unsigned old = atomicAdd(counter, 1u);   // init 0 -> last sees NBLK-1
        s_last = (old == (unsigned)(NBLK - 1)) ? 1u : 0u;
    }
    __syncthreads();
    if (s_last == 0u) return;
    __threadfence();

    // ---------- finisher (one block): sample + loss ----------
    {
        float cx = hdr[0], cy = hdr[1], cz = hdr[2], sc = hdr[3], ovl = hdr[4];
        float acc = 0.0f;
        for (int j = t; j < no; j += NTHR) {
            float qx = __fdiv_rn(__fsub_rn(ov[3 * j + 0], cx), sc);
            float qy = __fdiv_rn(__fsub_rn(ov[3 * j + 1], cy), sc);
            float qz = __fdiv_rn(__fsub_rn(ov[3 * j + 2], cz), sc);
            float fx = __fmul_rn(__fmul_rn(__fadd_rn(qx, 1.0f), 0.5f), 31.0f);
            float fy = __fmul_rn(__fmul_rn(__fadd_rn(qy, 1.0f), 0.5f), 31.0f);
            float fz = __fmul_rn(__fmul_rn(__fadd_rn(qz, 1.0f), 0.5f), 31.0f);
            float flx = floorf(fx), fly = floorf(fy), flz = floorf(fz);
            int ix0 = (int)flx, iy0 = (int)fly, iz0 = (int)flz;
            float w1x = __fsub_rn(fx, flx), w0x = __fsub_rn(1.0f, w1x);
            float w1y = __fsub_rn(fy, fly), w0y = __fsub_rn(1.0f, w1y);
            float w1z = __fsub_rn(fz, flz), w0z = __fsub_rn(1.0f, w1z);
            for (int dz = 0; dz < 2; ++dz)
                for (int dy = 0; dy < 2; ++dy)
                    for (int dx = 0; dx < 2; ++dx) {
                        int ix = ix0 + dx, iy = iy0 + dy, iz = iz0 + dz;
                        bool valid = (ix >= 0) & (ix < GN) & (iy >= 0) & (iy < GN) &
                                     (iz >= 0) & (iz < GN);
                        if (valid) {
                            // agent-scope loads: coherent vs other XCDs' atomics
                            unsigned pm = __hip_atomic_load(&parm[iy * GN + ix],
                                                __ATOMIC_RELAXED, __HIP_MEMORY_SCOPE_AGENT);
                            float val = 0.0f;
                            if ((pm >> iz) & 1u) {
                                unsigned du = __hip_atomic_load(&d2u[(iz * GN + iy) * GN + ix],
                                                __ATOMIC_RELAXED, __HIP_MEMORY_SCOPE_AGENT);
                                val = sqrtf(__uint_as_float(du));
                            }
                            float wgt = __fmul_rn(__fmul_rn(dx ? w1x : w0x, dy ? w1y : w0y),
                                                  dz ? w1z : w0z);
                            acc = __fadd_rn(acc, __fmul_rn(val, wgt));
                        }
                    }
        }
        acc = wsum64(acc);
        if (lane == 0) s_w[wvid][0] = acc;
        __syncthreads();
        if (wvid == 0) {
            float v = (lane < 16) ? s_w[lane][0] : 0.0f;
            v = wsum64(v);
            if (lane == 0) {
                float loss = __fmul_rn(v, v);
                out[0] = (ovl != 0.0f) ? loss : 0.0f;
            }
        }
    }
}

extern "C" void kernel_launch(void* const* d_in, const int* in_sizes, int n_in,
                              void* d_out, int out_size, void* d_ws, size_t ws_size,
                              hipStream_t stream) {
    const float* hv = (const float*)d_in[0];
    const float* ov = (const float*)d_in[1];
    const int* faces = (const int*)d_in[2];
    int nh = in_sizes[0] / 3;
    int no = in_sizes[1] / 3;
    int nf = in_sizes[2] / 3;

    unsigned* d2u = (unsigned*)d_ws;          // NPTS u32
    unsigned* parm = d2u + NPTS;              // NCOL u32
    unsigned* counter = parm + NCOL;          // 1 u32 (+pad)
    float* hdr = (float*)(counter + 16);      // 5 floats (+pad)
    float* fd = hdr + 16;                     // nf * FS floats

    k_prep<<<1, NTHR, 0, stream>>>(hv, nh, ov, no, faces, nf,
                                   hdr, fd, d2u, parm, counter);
    k_main<<<NBLK, NTHR, 0, stream>>>(fd, nf, d2u, parm, counter,
                                      hdr, ov, no, (float*)d_out);
}

// Round 11
// 177.379 us; speedup vs baseline: 1.2037x; 1.2037x over previous
//
#include <hip/hip_runtime.h>

#define EPSF 1e-12f
#define GN 32
#define NPTS (GN * GN * GN)
#define NCOL (GN * GN)
#define FSPLIT 16    // parity face-splits
#define NCG 16       // column-groups of 64 columns
#define NBLK (NCG * FSPLIT)
#define NTHR 1024
#define FS 20        // floats per face record
#define NFC 64       // distance-phase face chunks
#define NWAVES (NBLK * (NTHR / 64))

__device__ __forceinline__ float dot_rn(const float* x, const float* y) {
    return __fadd_rn(__fadd_rn(__fmul_rn(x[0], y[0]), __fmul_rn(x[1], y[1])),
                     __fmul_rn(x[2], y[2]));
}
__device__ __forceinline__ float wmin64(float v) {
    for (int o = 32; o > 0; o >>= 1) v = fminf(v, __shfl_xor(v, o));
    return v;
}
__device__ __forceinline__ float wmax64(float v) {
    for (int o = 32; o > 0; o >>= 1) v = fmaxf(v, __shfl_xor(v, o));
    return v;
}
__device__ __forceinline__ float wsum64(float v) {
    for (int o = 32; o > 0; o >>= 1) v += __shfl_xor(v, o);
    return v;
}

// ---------------- node 1: prep ----------------
// Inits buffers, bboxes -> hdr, face records -> fd, sampled-cell mask ->
// compacted cell list (clist, ncells). The mask uses the SAME __f*_rn index
// arithmetic as the finisher, so marked set == read set exactly.
__global__ void __launch_bounds__(NTHR) k_prep(
    const float* __restrict__ hv, int nh,
    const float* __restrict__ ov, int no,
    const int* __restrict__ faces, int nf,
    float* __restrict__ hdr, float* __restrict__ fd,
    unsigned* __restrict__ d2u, unsigned* __restrict__ parm,
    unsigned* __restrict__ counter, unsigned* __restrict__ clist,
    unsigned* __restrict__ ncells_g)
{
    __shared__ float s_w[16][12];
    __shared__ float s_hdr[4];
    __shared__ unsigned s_sm[NCOL];
    __shared__ unsigned s_nc;
    int t = threadIdx.x, lane = t & 63, wvid = t >> 6;

    for (int i = t; i < NPTS; i += NTHR) d2u[i] = 0x7f800000u;  // +inf bits
    if (t < NCOL) { parm[t] = 0u; s_sm[t] = 0u; }
    if (t == 0) { *counter = 0u; s_nc = 0u; }

    // ---- both bboxes ----
    float hmn[3] = { INFINITY, INFINITY, INFINITY };
    float hmx[3] = { -INFINITY, -INFINITY, -INFINITY };
    float omn[3] = { INFINITY, INFINITY, INFINITY };
    float omx[3] = { -INFINITY, -INFINITY, -INFINITY };
    for (int i = t; i < nh; i += NTHR)
        for (int k = 0; k < 3; ++k) {
            float v = hv[3 * i + k];
            hmn[k] = fminf(hmn[k], v); hmx[k] = fmaxf(hmx[k], v);
        }
    for (int i = t; i < no; i += NTHR)
        for (int k = 0; k < 3; ++k) {
            float v = ov[3 * i + k];
            omn[k] = fminf(omn[k], v); omx[k] = fmaxf(omx[k], v);
        }
    for (int k = 0; k < 3; ++k) {
        hmn[k] = wmin64(hmn[k]); hmx[k] = wmax64(hmx[k]);
        omn[k] = wmin64(omn[k]); omx[k] = wmax64(omx[k]);
    }
    if (lane == 0)
        for (int k = 0; k < 3; ++k) {
            s_w[wvid][k] = hmn[k]; s_w[wvid][3 + k] = hmx[k];
            s_w[wvid][6 + k] = omn[k]; s_w[wvid][9 + k] = omx[k];
        }
    __syncthreads();
    if (wvid == 0) {
        float r[12];
        for (int c = 0; c < 12; ++c) {
            bool ismin = (c < 3) || (c >= 6 && c < 9);
            float v = (lane < 16) ? s_w[lane][c] : (ismin ? INFINITY : -INFINITY);
            r[c] = ismin ? wmin64(v) : wmax64(v);
        }
        if (lane == 0) {
            bool ovl = true;
            for (int k = 0; k < 3; ++k)
                ovl = ovl && (r[k] <= r[9 + k]) && (r[6 + k] <= r[3 + k]);
            float e0 = __fsub_rn(r[3], r[0]);
            float e1 = __fsub_rn(r[4], r[1]);
            float e2 = __fsub_rn(r[5], r[2]);
            float m = fmaxf(e0, fmaxf(e1, e2));
            s_hdr[0] = __fmul_rn(0.5f, __fadd_rn(r[0], r[3]));
            s_hdr[1] = __fmul_rn(0.5f, __fadd_rn(r[1], r[4]));
            s_hdr[2] = __fmul_rn(0.5f, __fadd_rn(r[2], r[5]));
            s_hdr[3] = __fmul_rn(0.6f, m);
            hdr[0] = s_hdr[0]; hdr[1] = s_hdr[1]; hdr[2] = s_hdr[2];
            hdr[3] = s_hdr[3]; hdr[4] = ovl ? 1.0f : 0.0f;
        }
    }
    __syncthreads();
    float cx = s_hdr[0], cy = s_hdr[1], cz = s_hdr[2], sc = s_hdr[3];

    // ---- face records ----
    const float qnan = __int_as_float(0x7FC00000);
    for (int f = t; f < nf; f += NTHR) {
        int ia = faces[3 * f + 0], ib = faces[3 * f + 1], ic = faces[3 * f + 2];
        float v0[3], v1[3], v2[3];
        for (int k = 0; k < 3; ++k) {
            float cen = (k == 0) ? cx : ((k == 1) ? cy : cz);
            v0[k] = __fdiv_rn(__fsub_rn(hv[3 * ia + k], cen), sc);
            v1[k] = __fdiv_rn(__fsub_rn(hv[3 * ib + k], cen), sc);
            v2[k] = __fdiv_rn(__fsub_rn(hv[3 * ic + k], cen), sc);
        }
        float e0[3], e1[3];
        for (int k = 0; k < 3; ++k) {
            e0[k] = __fsub_rn(v1[k], v0[k]);
            e1[k] = __fsub_rn(v2[k], v0[k]);
        }
        float a = dot_rn(e0, e0);
        float b = dot_rn(e0, e1);
        float cc = dot_rn(e1, e1);
        float det = __fsub_rn(__fmul_rn(a, cc), __fmul_rn(b, b));
        float inv_det = (det > EPSF) ? (1.0f / det) : qnan;   // NaN-poison
        float inv_a = 1.0f / ((a > EPSF) ? a : 1.0f);
        float inv_c = 1.0f / ((cc > EPSF) ? cc : 1.0f);
        float ee2 = __fsub_rn(__fadd_rn(a, cc), __fmul_rn(2.0f, b));
        float inv_ee2 = 1.0f / ((ee2 > EPSF) ? ee2 : 1.0f);
        float det2 = __fsub_rn(__fmul_rn(e0[0], e1[1]), __fmul_rn(e1[0], e0[1]));
        float inv_det2s = (fabsf(det2) > EPSF) ? (1.0f / det2) : qnan;
        float* o = fd + (size_t)f * FS;
        o[0] = v0[0]; o[1] = v0[1]; o[2] = v0[2];
        o[3] = e0[0]; o[4] = e0[1]; o[5] = e0[2];
        o[6] = e1[0]; o[7] = e1[1]; o[8] = e1[2];
        o[9] = a; o[10] = b; o[11] = cc;
        o[12] = inv_det; o[13] = inv_a; o[14] = inv_c;
        o[15] = ee2; o[16] = inv_ee2; o[17] = inv_det2s;
        o[18] = __fsub_rn(b, a); o[19] = 0.f;
    }

    // ---- sampled-cell mask (identical index arithmetic to finisher) ----
    for (int j = t; j < no; j += NTHR) {
        float qx = __fdiv_rn(__fsub_rn(ov[3 * j + 0], cx), sc);
        float qy = __fdiv_rn(__fsub_rn(ov[3 * j + 1], cy), sc);
        float qz = __fdiv_rn(__fsub_rn(ov[3 * j + 2], cz), sc);
        float fx = __fmul_rn(__fmul_rn(__fadd_rn(qx, 1.0f), 0.5f), 31.0f);
        float fy = __fmul_rn(__fmul_rn(__fadd_rn(qy, 1.0f), 0.5f), 31.0f);
        float fz = __fmul_rn(__fmul_rn(__fadd_rn(qz, 1.0f), 0.5f), 31.0f);
        int ix0 = (int)floorf(fx), iy0 = (int)floorf(fy), iz0 = (int)floorf(fz);
        for (int dz = 0; dz < 2; ++dz)
            for (int dy = 0; dy < 2; ++dy)
                for (int dx = 0; dx < 2; ++dx) {
                    int ix = ix0 + dx, iy = iy0 + dy, iz = iz0 + dz;
                    if ((ix >= 0) & (ix < GN) & (iy >= 0) & (iy < GN) &
                        (iz >= 0) & (iz < GN))
                        atomicOr(&s_sm[iy * GN + ix], 1u << iz);
                }
    }
    __syncthreads();
    // ---- compact sampled cells into clist ----
    for (int i = t; i < NPTS; i += NTHR) {
        if ((s_sm[i & (NCOL - 1)] >> (i >> 10)) & 1u) {
            unsigned pos = atomicAdd(&s_nc, 1u);
            clist[pos] = (unsigned)i;   // cell id: gz*1024 + gy*32 + gx
        }
    }
    __syncthreads();
    if (t == 0) *ncells_g = s_nc;
}

// ---------------- node 2: main (parity + sampled-cell distance + finisher) ----------------
__global__ void __launch_bounds__(NTHR) k_main(
    const float* __restrict__ fd, int nf,
    unsigned* __restrict__ d2u, unsigned* __restrict__ parm,
    unsigned* __restrict__ counter,
    const unsigned* __restrict__ clist, const unsigned* __restrict__ ncells_g,
    const float* __restrict__ hdr,
    const float* __restrict__ ov, int no,
    float* __restrict__ out)
{
    __shared__ unsigned s_pm[64];
    __shared__ float s_w[16][8];
    __shared__ unsigned s_last;

    int t = threadIdx.x, lane = t & 63, wvid = t >> 6;
    int fs = blockIdx.x >> 4;   // parity face-split
    int cg = blockIdx.x & 15;   // parity column-group
    const float step = 2.0f / 31.0f;

    if (t < 64) s_pm[t] = 0u;
    __syncthreads();

    // ---------- phase P: parity (verbatim bit-exact path from R4-R10) ----------
    {
        int col = cg * 64 + lane;           // gy*32+gx
        int gx = col & 31, gy = col >> 5;
        float px = __fadd_rn(-1.0f, __fmul_rn((float)gx, step));
        float py = __fadd_rn(-1.0f, __fmul_rn((float)gy, step));

        int chunkB = (nf + FSPLIT - 1) / FSPLIT;
        int f0B = fs * chunkB;
        int nloc = min(nf, f0B + chunkB) - f0B;
        int f0 = __builtin_amdgcn_readfirstlane(f0B + (wvid * nloc) / 16);
        int f1 = __builtin_amdgcn_readfirstlane(f0B + ((wvid + 1) * nloc) / 16);

        unsigned cmask = 0u;
        for (int f = f0; f < f1; ++f) {
            const float* q = fd + (size_t)f * FS;
            float v0x = q[0], v0y = q[1], v0z = q[2];
            float e0x = q[3], e0y = q[4], e0z = q[5];
            float e1y = q[7], e1x = q[6];
            float inv_det2s = q[17];
            float e1z = q[8];

            float wx = __fsub_rn(px, v0x), wy = __fsub_rn(py, v0y);
            float u2n = __fsub_rn(__fmul_rn(wx, e1y), __fmul_rn(wy, e1x));
            float v2n = __fsub_rn(__fmul_rn(e0x, wy), __fmul_rn(e0y, wx));
            float u2 = __fmul_rn(u2n, inv_det2s);
            float v2 = __fmul_rn(v2n, inv_det2s);
            bool in2d = (u2 >= 0.0f) & (v2 >= 0.0f) & (__fadd_rn(u2, v2) <= 1.0f);
            float zint = __fadd_rn(__fadd_rn(v0z, __fmul_rn(u2, e0z)), __fmul_rn(v2, e1z));
            int c = 0;
            {
                float p;
                p = __fadd_rn(-1.0f, __fmul_rn((float)(15), step));      if (zint > p) c = 16;
                p = __fadd_rn(-1.0f, __fmul_rn((float)(c + 7), step));   if (zint > p) c += 8;
                p = __fadd_rn(-1.0f, __fmul_rn((float)(c + 3), step));   if (zint > p) c += 4;
                p = __fadd_rn(-1.0f, __fmul_rn((float)(c + 1), step));   if (zint > p) c += 2;
                p = __fadd_rn(-1.0f, __fmul_rn((float)(c), step));       if (zint > p) c += 1;
                p = __fadd_rn(-1.0f, __fmul_rn((float)(c), step));       if (zint > p) c += 1;
            }
            unsigned mask = (c == 0) ? 0u : (0xffffffffu >> (32 - c));
            cmask ^= in2d ? mask : 0u;
        }
        atomicXor(&s_pm[lane], cmask);
        __syncthreads();
        if (t < 64) atomicXor(&parm[cg * 64 + t], s_pm[t]);
    }

    // ---------- phase D: distance for sampled cells only, per-lane-cell ----------
    {
        unsigned nc = *ncells_g;
        unsigned nbatch = (nc + 63) >> 6;
        unsigned ntiles = nbatch * NFC;
        int fchunk = (nf + NFC - 1) / NFC;
        unsigned w = (unsigned)(blockIdx.x * 16 + wvid);

        for (unsigned tt = w; tt < ntiles; tt += NWAVES) {
            unsigned cb = tt / NFC;
            unsigned fc = tt - cb * NFC;
            unsigned idx = cb * 64 + (unsigned)lane;
            bool valid = idx < nc;
            unsigned cell = valid ? clist[idx] : 0u;
            int gx = cell & 31, gy = (cell >> 5) & 31, gz = cell >> 10;
            float px = __fadd_rn(-1.0f, __fmul_rn((float)gx, step));
            float py = __fadd_rn(-1.0f, __fmul_rn((float)gy, step));
            float pz = __fadd_rn(-1.0f, __fmul_rn((float)gz, step));

            int f0 = __builtin_amdgcn_readfirstlane((int)fc * fchunk);
            int f1 = __builtin_amdgcn_readfirstlane(min(nf, (int)(fc + 1) * fchunk));

            float dmin = 3.402823466e38f;
            for (int f = f0; f < f1; ++f) {
                const float* q = fd + (size_t)f * FS;   // wave-uniform -> s_load
                float v0x = q[0], v0y = q[1], v0z = q[2];
                float e0x = q[3], e0y = q[4], e0z = q[5];
                float e1x = q[6], e1y = q[7], e1z = q[8];
                float a = q[9], b = q[10], cc = q[11];
                float inv_det = q[12], inv_a = q[13], inv_c = q[14];
                float ee2 = q[15], inv_ee2 = q[16];
                float bma = q[18];

                float wx = __fsub_rn(px, v0x), wy = __fsub_rn(py, v0y);
                float wz = __fsub_rn(pz, v0z);
                float ff = wx * wx + wy * wy + wz * wz;
                float de0 = wx * e0x + wy * e0y + wz * e0z;
                float de1 = wx * e1x + wy * e1y + wz * e1z;
                float u = (cc * de0 - b * de1) * inv_det;
                float v = (a * de1 - b * de0) * inv_det;
                bool inside = (u >= 0.0f) & (v >= 0.0f) & (u + v <= 1.0f);  // NaN->false
                float plane_d2 = ff - (u * de0 + v * de1);
                float t0 = fminf(fmaxf(de0 * inv_a, 0.0f), 1.0f);
                float d2_0 = ff + t0 * (t0 * a - 2.0f * de0);
                float t1 = fminf(fmaxf(de1 * inv_c, 0.0f), 1.0f);
                float d2_1 = ff + t1 * (t1 * cc - 2.0f * de1);
                float dot2 = (de1 - de0) - bma;
                float w1sq = ff - 2.0f * de0 + a;
                float t2 = fminf(fmaxf(dot2 * inv_ee2, 0.0f), 1.0f);
                float d2_2 = w1sq + t2 * (t2 * ee2 - 2.0f * dot2);
                float ed2 = fminf(fminf(d2_0, d2_1), d2_2);
                float d2 = inside ? plane_d2 : ed2;
                dmin = fminf(dmin, fmaxf(d2, 0.0f));
            }
            if (valid)
                atomicMin(&d2u[cell], __float_as_uint(dmin));
        }
    }

    // ---------- completion counter: last block finishes ----------
    __threadfence();
    __syncthreads();
    if (t == 0) {
        unsigned old = atomicAdd(counter, 1u);
        s_last = (old == (unsigned)(NBLK - 1)) ? 1u : 0u;
    }
    __syncthreads();
    if (s_last == 0u) return;
    __threadfence();

    // ---------- finisher (one block): sample + loss ----------
    {
        float cx = hdr[0], cy = hdr[1], cz = hdr[2], sc = hdr[3], ovl = hdr[4];
        float acc = 0.0f;
        for (int j = t; j < no; j += NTHR) {
            float qx = __fdiv_rn(__fsub_rn(ov[3 * j + 0], cx), sc);
            float qy = __fdiv_rn(__fsub_rn(ov[3 * j + 1], cy), sc);
            float qz = __fdiv_rn(__fsub_rn(ov[3 * j + 2], cz), sc);
            float fx = __fmul_rn(__fmul_rn(__fadd_rn(qx, 1.0f), 0.5f), 31.0f);
            float fy = __fmul_rn(__fmul_rn(__fadd_rn(qy, 1.0f), 0.5f), 31.0f);
            float fz = __fmul_rn(__fmul_rn(__fadd_rn(qz, 1.0f), 0.5f), 31.0f);
            float flx = floorf(fx), fly = floorf(fy), flz = floorf(fz);
            int ix0 = (int)flx, iy0 = (int)fly, iz0 = (int)flz;
            float w1x = __fsub_rn(fx, flx), w0x = __fsub_rn(1.0f, w1x);
            float w1y = __fsub_rn(fy, fly), w0y = __fsub_rn(1.0f, w1y);
            float w1z = __fsub_rn(fz, flz), w0z = __fsub_rn(1.0f, w1z);
            for (int dz = 0; dz < 2; ++dz)
                for (int dy = 0; dy < 2; ++dy)
                    for (int dx = 0; dx < 2; ++dx) {
                        int ix = ix0 + dx, iy = iy0 + dy, iz = iz0 + dz;
                        bool valid = (ix >= 0) & (ix < GN) & (iy >= 0) & (iy < GN) &
                                     (iz >= 0) & (iz < GN);
                        if (valid) {
                            unsigned pm = __hip_atomic_load(&parm[iy * GN + ix],
                                                __ATOMIC_RELAXED, __HIP_MEMORY_SCOPE_AGENT);
                            float val = 0.0f;
                            if ((pm >> iz) & 1u) {
                                unsigned du = __hip_atomic_load(&d2u[(iz * GN + iy) * GN + ix],
                                                __ATOMIC_RELAXED, __HIP_MEMORY_SCOPE_AGENT);
                                val = sqrtf(__uint_as_float(du));
                            }
                            float wgt = __fmul_rn(__fmul_rn(dx ? w1x : w0x, dy ? w1y : w0y),
                                                  dz ? w1z : w0z);
                            acc = __fadd_rn(acc, __fmul_rn(val, wgt));
                        }
                    }
        }
        acc = wsum64(acc);
        if (lane == 0) s_w[wvid][0] = acc;
        __syncthreads();
        if (wvid == 0) {
            float v = (lane < 16) ? s_w[lane][0] : 0.0f;
            v = wsum64(v);
            if (lane == 0) {
                float loss = __fmul_rn(v, v);
                out[0] = (ovl != 0.0f) ? loss : 0.0f;
            }
        }
    }
}

extern "C" void kernel_launch(void* const* d_in, const int* in_sizes, int n_in,
                              void* d_out, int out_size, void* d_ws, size_t ws_size,
                              hipStream_t stream) {
    const float* hv = (const float*)d_in[0];
    const float* ov = (const float*)d_in[1];
    const int* faces = (const int*)d_in[2];
    int nh = in_sizes[0] / 3;
    int no = in_sizes[1] / 3;
    int nf = in_sizes[2] / 3;

    unsigned* d2u = (unsigned*)d_ws;          // NPTS u32
    unsigned* parm = d2u + NPTS;              // NCOL u32
    unsigned* counter = parm + NCOL;          // u32
    unsigned* ncells_g = counter + 1;         // u32 (+pad to 16)
    unsigned* clist = counter + 16;           // NPTS u32 max
    float* hdr = (float*)(clist + NPTS);      // 5 floats (+pad to 16)
    float* fd = hdr + 16;                     // nf * FS floats

    k_prep<<<1, NTHR, 0, stream>>>(hv, nh, ov, no, faces, nf,
                                   hdr, fd, d2u, parm, counter, clist, ncells_g);
    k_main<<<NBLK, NTHR, 0, stream>>>(fd, nf, d2u, parm, counter,
                                      clist, ncells_g, hdr, ov, no, (float*)d_out);
}